// Round 5
// baseline (37487.177 us; speedup 1.0000x reference)
//
#include <hip/hip_runtime.h>
#include <cstddef>
#include <cstdint>

#define HID     1024
#define BATCH   64
#define TSEQ    512
#define NB      (BATCH*HID)     // 65536 floats per [B,H] slab
#define NBLK    256
#define NITER   515
#define RSTRIDE 20              // LDS reduction row stride (16 + pad 4)
#define HSTRIDE 129             // LDS h-chunk row stride (128 + pad 1)

// ---------------------------------------------------------------------------
// ws layout (floats), P = slot rotation depth (16/8/4/2 chosen from ws_size):
//  [0,            P*NB)    h0 slots   (slot t&(P-1) holds h0[t])
//  [P*NB,       2*P*NB)    h1 slots
//  [2*P*NB,     3*P*NB)    ig1 slots  (igate1[t] + bx1 + bh1)
//  [3*P*NB]                barrier counter (unsigned, zeroed by memset)
//
// Coherence model (measured-good in R4):
//  - cross-block slab STORES are sc1 write-through (reach the MALL before the
//    barrier count increments; invalidation can never lose data).
//  - slab LOADS are plain/cached; an agent-acquire fence every P iterations
//    kills any cached slab line before its slot is re-read (slot S is read
//    once per P, rewritten once per P; exactly one fence lands between any
//    cache-fill and the next read of that slot).
//
// R5 change — coalesced h-path via LDS transpose:
//  The old dot engine read h with lane<->batch mapping (stride-4KB across
//  lanes: every dwordx4 = 64 distinct cache lines -> TA/tag-pipe serialized,
//  36.7 us/iter at 585 GB/s effective). Now each 128-k chunk is staged
//  coalesced (lane<->k) into LDS, and threads ds_read their k-slice.
//  K ownership interleaved: wave q owns k in {128*cc + 16q + j, j=0..15}
//  so each staged chunk feeds all 8 waves. W scalar path unchanged
//  (wave-uniform s_load, now 16-float rows per chunk, 64B-aligned).
// ---------------------------------------------------------------------------

typedef __attribute__((ext_vector_type(2))) float f32x2;

__device__ __forceinline__ void gstore2_coh(float* p, f32x2 v) {
  asm volatile("global_store_dwordx2 %0, %1, off sc1" :: "v"(p), "v"(v) : "memory");
}

__device__ __forceinline__ void gbar(unsigned* bar, unsigned target) {
  // Drain this wave's write-through stores to the coherence point, then
  // block-barrier so ALL waves' stores are drained before thread 0 arrives.
  asm volatile("s_waitcnt vmcnt(0)" ::: "memory");
  __syncthreads();
  if (threadIdx.x == 0) {
    __hip_atomic_fetch_add(bar, 1u, __ATOMIC_RELAXED, __HIP_MEMORY_SCOPE_AGENT);
    while (__hip_atomic_load(bar, __ATOMIC_RELAXED, __HIP_MEMORY_SCOPE_AGENT) < target) {
      __builtin_amdgcn_s_sleep(1);
    }
  }
  __syncthreads();
}

// ---------------------------------------------------------------------------
// Persistent cooperative pipelined recurrence, 256 blocks x 512 threads.
// Roles (blk>>6), iteration i:
//   3: ig0[t=i]   = x[t] @ Wx0^T + bx0 + bh0       -> io[t]      (sc1 store)
//   0: h0[t=i-1]  = tanh(ig0[t] + h0[t-1] @ Wh0^T) -> slot t&m   (sc1 store)
//   1: ig1[t=i-2] = h0[t] @ Wx1^T + bx1 + bh1      -> slot t&m   (sc1 store)
//   2: h1[t=i-3]  = tanh(ig1[t] + h1[t-1] @ Wh1^T); io[t] = 10*h1 (plain)
// ---------------------------------------------------------------------------
__global__ __launch_bounds__(512, 4) void rnn_step(
    const float* __restrict__ x,
    float* io,                          // d_out: ig0 scratch AND output sink
    const float* __restrict__ h0_init,  // [2][B][H]
    const float* __restrict__ Wx,       // [2][H][H]
    const float* __restrict__ Wh,       // [2][H][H]
    const float* __restrict__ bx,       // [2][H]
    const float* __restrict__ bh,       // [2][H]
    float* __restrict__ ws,
    unsigned P, unsigned mask)
{
  __shared__ __align__(16) float red[8 * 64 * RSTRIDE];   // 40 KB
  __shared__ __align__(16) float hbuf[64 * HSTRIDE];      // 33 KB (1 chunk)
  const int tid  = threadIdx.x;
  const int blk  = blockIdx.x;
  const int role = blk >> 6;                 // 0..3
  const int c0   = (blk & 63) << 4;          // 16 cols per block
  const int b    = tid & 63;                 // lane = batch row for compute
  const int kq   = __builtin_amdgcn_readfirstlane(tid >> 6); // wave id 0..7

  // Coalesced staging assignment: thread covers 4 rows (r*16 + tid>>5) at
  // k-offset (tid&31)*4 within the current 128-k chunk.
  const int srow = tid >> 5;                 // 0..15
  const int skol = (tid & 31) << 2;          // 0,4,...,124

  float* h0base = ws;
  float* h1base = ws + (size_t)P * NB;
  float* igbase = ws + (size_t)2 * P * NB;
  unsigned* bar = (unsigned*)(ws + (size_t)3 * P * NB);

  const float* W = (role == 3) ? Wx
                 : (role == 0) ? Wh
                 : (role == 1) ? (Wx + (size_t)HID * HID)
                 :               (Wh + (size_t)HID * HID);
  // Wave q's k-elements within chunk cc: k = cc*128 + q*16 + j, j=0..15.
  const float* Wb = W + (size_t)c0 * HID + kq * 16;

  // Epilogue output assignment: 2 outputs per thread, o = 2*tid, 2*tid+1.
  const int o0 = tid * 2;
  const int b1 = o0 >> 4;                    // batch row of outputs
  const int c1 = o0 & 15;                    // local col (even)
  const size_t rb = (size_t)b1 * HID + c0 + c1;

  float bsum0 = 0.f, bsum1 = 0.f;
  if (role == 1) {
    bsum0 = bx[HID + c0 + c1]     + bh[HID + c0 + c1];
    bsum1 = bx[HID + c0 + c1 + 1] + bh[HID + c0 + c1 + 1];
  } else if (role == 3) {
    bsum0 = bx[c0 + c1]     + bh[c0 + c1];
    bsum1 = bx[c0 + c1 + 1] + bh[c0 + c1 + 1];
  }

  for (int i = 0; i < NITER; ++i) {
    // Periodic coherence fence (grid-uniform): see model above.
    if ((i & (int)mask) == 0 && i) {
      __builtin_amdgcn_fence(__ATOMIC_ACQUIRE, "agent");
    }

    bool active;
    int t;
    const float* src;
    if (role == 3)      { t = i;     active = (i <= 511);           src = x + (size_t)t * NB; }
    else if (role == 0) { t = i - 1; active = (i >= 1 && i <= 512);
                          src = (t == 0) ? h0_init : h0base + (size_t)((t - 1) & mask) * NB; }
    else if (role == 1) { t = i - 2; active = (i >= 2 && i <= 513);
                          src = h0base + (size_t)(t & mask) * NB; }
    else                { t = i - 3; active = (i >= 3 && i <= 514);
                          src = (t == 0) ? (h0_init + NB) : h1base + (size_t)((t - 1) & mask) * NB; }

    if (active) {
      // Epilogue operands (produced >=1 iteration ago; plain cached loads).
      float e0 = 0.f, e1 = 0.f;
      if (role == 0)      { e0 = io[(size_t)t * NB + rb];
                            e1 = io[(size_t)t * NB + rb + 1]; }
      else if (role == 2) { const float* ig = igbase + (size_t)(t & mask) * NB;
                            e0 = ig[rb]; e1 = ig[rb + 1]; }

      f32x2 acc[16];
#pragma unroll
      for (int c = 0; c < 16; ++c) acc[c] = f32x2{0.f, 0.f};

      // Preload chunk 0 (coalesced: consecutive lanes -> consecutive k).
      float4 stA[4], stB[4];
#pragma unroll
      for (int r = 0; r < 4; ++r)
        stA[r] = *(const float4*)(src + (size_t)(r * 16 + srow) * HID + skol);

#pragma unroll 1
      for (int cc = 0; cc < 8; ++cc) {
        __syncthreads();             // prior chunk's LDS reads complete
        const float4* stw = (cc & 1) ? stB : stA;
#pragma unroll
        for (int r = 0; r < 4; ++r)
          *(float4*)&hbuf[(r * 16 + srow) * HSTRIDE + skol] = stw[r];
        if (cc < 7) {                // prefetch next chunk during compute
          float4* stn = (cc & 1) ? stA : stB;
#pragma unroll
          for (int r = 0; r < 4; ++r)
            stn[r] = *(const float4*)(src + (size_t)(r * 16 + srow) * HID
                                      + (cc + 1) * 128 + skol);
        }
        __syncthreads();             // hbuf chunk visible

        // My 16 k-values for this chunk (2-way bank access = free).
        const float* hr = &hbuf[b * HSTRIDE + kq * 16];
        float4 h0v = *(const float4*)(hr + 0);
        float4 h1v = *(const float4*)(hr + 4);
        float4 h2v = *(const float4*)(hr + 8);
        float4 h3v = *(const float4*)(hr + 12);

        const float* Wc = Wb + cc * 128;   // wave-uniform -> s_load
#pragma unroll 4
        for (int c = 0; c < 16; ++c) {
          const float* w = Wc + (size_t)c * HID;
          float4 w0 = *(const float4*)(w + 0);
          float4 w1 = *(const float4*)(w + 4);
          float4 w2 = *(const float4*)(w + 8);
          float4 w3 = *(const float4*)(w + 12);
          f32x2 s = acc[c];
          s += f32x2{h0v.x, h0v.y} * f32x2{w0.x, w0.y};
          s += f32x2{h0v.z, h0v.w} * f32x2{w0.z, w0.w};
          s += f32x2{h1v.x, h1v.y} * f32x2{w1.x, w1.y};
          s += f32x2{h1v.z, h1v.w} * f32x2{w1.z, w1.w};
          s += f32x2{h2v.x, h2v.y} * f32x2{w2.x, w2.y};
          s += f32x2{h2v.z, h2v.w} * f32x2{w2.z, w2.w};
          s += f32x2{h3v.x, h3v.y} * f32x2{w3.x, w3.y};
          s += f32x2{h3v.z, h3v.w} * f32x2{w3.z, w3.w};
          acc[c] = s;
        }
      }

      // Collapse even/odd-k partials, then kq-reduction through LDS.
      float accs[16];
#pragma unroll
      for (int c = 0; c < 16; ++c) accs[c] = acc[c].x + acc[c].y;

      float* rrow = &red[(kq * 64 + b) * RSTRIDE];
      *(float4*)(rrow + 0)  = make_float4(accs[0],  accs[1],  accs[2],  accs[3]);
      *(float4*)(rrow + 4)  = make_float4(accs[4],  accs[5],  accs[6],  accs[7]);
      *(float4*)(rrow + 8)  = make_float4(accs[8],  accs[9],  accs[10], accs[11]);
      *(float4*)(rrow + 12) = make_float4(accs[12], accs[13], accs[14], accs[15]);
      __syncthreads();

      float s0 = 0.f, s1 = 0.f;
#pragma unroll
      for (int q = 0; q < 8; ++q) {
        s0 += red[(q * 64 + b1) * RSTRIDE + c1];
        s1 += red[(q * 64 + b1) * RSTRIDE + c1 + 1];
      }

      if (role == 3) {
        f32x2 o = { s0 + bsum0, s1 + bsum1 };
        gstore2_coh(io + (size_t)t * NB + rb, o);
      } else if (role == 0) {
        f32x2 o = { tanhf(s0 + e0), tanhf(s1 + e1) };
        gstore2_coh(h0base + (size_t)(t & mask) * NB + rb, o);
      } else if (role == 1) {
        f32x2 o = { s0 + bsum0, s1 + bsum1 };
        gstore2_coh(igbase + (size_t)(t & mask) * NB + rb, o);
      } else {
        float t0 = tanhf(s0 + e0);
        float t1 = tanhf(s1 + e1);
        f32x2 o = { t0, t1 };
        gstore2_coh(h1base + (size_t)(t & mask) * NB + rb, o);
        // Final output: plain store; kernel-end release flushes dirty L2.
        *(float2*)&io[(size_t)t * NB + rb] = make_float2(10.f * t0, 10.f * t1);
      }
      // red/hbuf reuse next iter is fenced by gbar's __syncthreads.
    }
    gbar(bar, (unsigned)(NBLK * (i + 1)));
  }
}

// ---------------------------------------------------------------------------
// Finalize: h_n = [h0[511], h1[511]] (slot 511&mask; written by sc1
// write-through stores -> fresh at the MALL; this dispatch's acquire
// invalidates caches so plain loads see it).
// ---------------------------------------------------------------------------
__global__ __launch_bounds__(256) void finalize_hn(
    const float* __restrict__ ws, float* __restrict__ out, unsigned P, unsigned mask)
{
  const int g = blockIdx.x * 256 + threadIdx.x;     // 0..131071
  const float* h0f = ws + (size_t)(511u & mask) * NB;
  const float* h1f = ws + (size_t)(P + (511u & mask)) * NB;
  const float v = (g < NB) ? h0f[g] : h1f[g - NB];
  out[(size_t)TSEQ * NB + g] = v;
}

// ---------------------------------------------------------------------------
extern "C" void kernel_launch(void* const* d_in, const int* in_sizes, int n_in,
                              void* d_out, int out_size, void* d_ws, size_t ws_size,
                              hipStream_t stream) {
  const float* x  = (const float*)d_in[0];
  const float* h0 = (const float*)d_in[1];
  const float* Wx = (const float*)d_in[2];
  const float* bx = (const float*)d_in[3];
  const float* Wh = (const float*)d_in[4];
  const float* bh = (const float*)d_in[5];
  float* out = (float*)d_out;
  float* ws  = (float*)d_ws;

  // Pick the deepest slot rotation that fits the workspace (16 -> 12.6 MB).
  // P=2 floor has byte-identical footprint to the previously-verified layout.
  unsigned P = 16;
  while (P > 2 && ((size_t)3 * P * NB + 16) * sizeof(float) > ws_size) P >>= 1;
  unsigned mask = P - 1;

  // Zero the barrier counter (stream-ordered, graph-capture safe).
  hipMemsetAsync(ws + (size_t)3 * P * NB, 0, sizeof(unsigned), stream);

  float* io = out;
  void* args[] = { &x, &io, &h0, &Wx, &Wh, &bx, &bh, &ws, &P, &mask };
  hipLaunchCooperativeKernel((const void*)rnn_step, dim3(NBLK), dim3(512),
                             args, 0, stream);

  finalize_hn<<<dim3(512), dim3(256), 0, stream>>>(ws, out, P, mask);
}

// Round 6
// 33504.788 us; speedup vs baseline: 1.1189x; 1.1189x over previous
//
#include <hip/hip_runtime.h>
#include <cstddef>
#include <cstdint>

#define HID     1024
#define BATCH   64
#define TSEQ    512
#define NB      (BATCH*HID)     // 65536 floats per [B,H] slab
#define NBLK    256
#define NITER   515
#define RSTRIDE 20              // LDS reduction row stride (16 + pad 4)
#define HSTRIDE 132             // LDS h-chunk row stride: 132 = 4 mod 32 ->
                                // lane b's 16B quad starts at bank 4(b+..):
                                // 8 consecutive lanes tile all 32 banks once
                                // -> conflict-free ds_read_b128. (129 was
                                // 1 mod 32 -> overlapping quads, ~4-way.)

// ---------------------------------------------------------------------------
// ws layout (floats), P = slot rotation depth (16/8/4/2 chosen from ws_size):
//  [0,            P*NB)    h0 slots   (slot t&(P-1) holds h0[t])
//  [P*NB,       2*P*NB)    h1 slots
//  [2*P*NB,     3*P*NB)    ig1 slots  (igate1[t] + bx1 + bh1)
//  [3*P*NB]                barrier counter (unsigned, zeroed by memset)
//
// Coherence model (measured-good in R4):
//  - cross-block slab STORES are sc1 write-through (reach the MALL before the
//    barrier count increments; invalidation can never lose data).
//  - slab LOADS are plain/cached; an agent-acquire fence every P iterations
//    kills any cached slab line before its slot is re-read.
//
// R6 changes vs R5 (which regressed 19.3 -> 37.5 ms):
//  - scratch-spill fix: R5's `(cc&1) ? stB : stA` runtime pointer-select
//    forced the staging arrays to scratch (WRITE_SIZE 35x). Now an explicit
//    two-phase loop with NAMED stA/stB and static indexing only.
//  - HSTRIDE 129 -> 132 (see above).
// ---------------------------------------------------------------------------

typedef __attribute__((ext_vector_type(2))) float f32x2;

__device__ __forceinline__ void gstore2_coh(float* p, f32x2 v) {
  asm volatile("global_store_dwordx2 %0, %1, off sc1" :: "v"(p), "v"(v) : "memory");
}

__device__ __forceinline__ void gbar(unsigned* bar, unsigned target) {
  // Drain this wave's write-through stores to the coherence point, then
  // block-barrier so ALL waves' stores are drained before thread 0 arrives.
  asm volatile("s_waitcnt vmcnt(0)" ::: "memory");
  __syncthreads();
  if (threadIdx.x == 0) {
    __hip_atomic_fetch_add(bar, 1u, __ATOMIC_RELAXED, __HIP_MEMORY_SCOPE_AGENT);
    while (__hip_atomic_load(bar, __ATOMIC_RELAXED, __HIP_MEMORY_SCOPE_AGENT) < target) {
      __builtin_amdgcn_s_sleep(1);
    }
  }
  __syncthreads();
}

// Coalesced global->reg load of one 128-k chunk slice (4 rows x 16B/lane;
// consecutive lanes -> consecutive k => 512B contiguous runs per wave).
__device__ __forceinline__ void load_chunk(float4 (&st)[4], const float* src,
                                           int srow, int skol, int cc) {
#pragma unroll
  for (int r = 0; r < 4; ++r)
    st[r] = *(const float4*)(src + (size_t)(r * 16 + srow) * HID + cc * 128 + skol);
}

// Reg->LDS store of the staged slice (contiguous 512B runs per wave row:
// conflict-free).
__device__ __forceinline__ void write_chunk(float* hbuf, const float4 (&st)[4],
                                            int srow, int skol) {
#pragma unroll
  for (int r = 0; r < 4; ++r)
    *(float4*)&hbuf[(r * 16 + srow) * HSTRIDE + skol] = st[r];
}

// One 16-col x 16-k FMA section from LDS-transposed h. hr points at this
// thread's (batch b, wave-k-slice) row; Wc is wave-uniform -> s_load.
__device__ __forceinline__ void compute_chunk(f32x2 (&acc)[16],
                                              const float* hr, const float* Wc) {
  float4 h0v = *(const float4*)(hr + 0);
  float4 h1v = *(const float4*)(hr + 4);
  float4 h2v = *(const float4*)(hr + 8);
  float4 h3v = *(const float4*)(hr + 12);
#pragma unroll 4
  for (int c = 0; c < 16; ++c) {
    const float* w = Wc + (size_t)c * HID;
    float4 w0 = *(const float4*)(w + 0);
    float4 w1 = *(const float4*)(w + 4);
    float4 w2 = *(const float4*)(w + 8);
    float4 w3 = *(const float4*)(w + 12);
    f32x2 s = acc[c];
    s += f32x2{h0v.x, h0v.y} * f32x2{w0.x, w0.y};
    s += f32x2{h0v.z, h0v.w} * f32x2{w0.z, w0.w};
    s += f32x2{h1v.x, h1v.y} * f32x2{w1.x, w1.y};
    s += f32x2{h1v.z, h1v.w} * f32x2{w1.z, w1.w};
    s += f32x2{h2v.x, h2v.y} * f32x2{w2.x, w2.y};
    s += f32x2{h2v.z, h2v.w} * f32x2{w2.z, w2.w};
    s += f32x2{h3v.x, h3v.y} * f32x2{w3.x, w3.y};
    s += f32x2{h3v.z, h3v.w} * f32x2{w3.z, w3.w};
    acc[c] = s;
  }
}

// ---------------------------------------------------------------------------
// Persistent cooperative pipelined recurrence, 256 blocks x 512 threads.
// Roles (blk>>6), iteration i:
//   3: ig0[t=i]   = x[t] @ Wx0^T + bx0 + bh0       -> io[t]      (sc1 store)
//   0: h0[t=i-1]  = tanh(ig0[t] + h0[t-1] @ Wh0^T) -> slot t&m   (sc1 store)
//   1: ig1[t=i-2] = h0[t] @ Wx1^T + bx1 + bh1      -> slot t&m   (sc1 store)
//   2: h1[t=i-3]  = tanh(ig1[t] + h1[t-1] @ Wh1^T); io[t] = 10*h1 (plain)
// ---------------------------------------------------------------------------
__global__ __launch_bounds__(512, 4) void rnn_step(
    const float* __restrict__ x,
    float* io,                          // d_out: ig0 scratch AND output sink
    const float* __restrict__ h0_init,  // [2][B][H]
    const float* __restrict__ Wx,       // [2][H][H]
    const float* __restrict__ Wh,       // [2][H][H]
    const float* __restrict__ bx,       // [2][H]
    const float* __restrict__ bh,       // [2][H]
    float* __restrict__ ws,
    unsigned P, unsigned mask)
{
  __shared__ __align__(16) float red[8 * 64 * RSTRIDE];   // 40 KB
  __shared__ __align__(16) float hbuf[64 * HSTRIDE];      // 33 KB (1 chunk)
  const int tid  = threadIdx.x;
  const int blk  = blockIdx.x;
  const int role = blk >> 6;                 // 0..3
  const int c0   = (blk & 63) << 4;          // 16 cols per block
  const int b    = tid & 63;                 // lane = batch row for compute
  const int kq   = __builtin_amdgcn_readfirstlane(tid >> 6); // wave id 0..7

  // Coalesced staging assignment: thread covers 4 rows (r*16 + tid>>5) at
  // k-offset (tid&31)*4 within the current 128-k chunk.
  const int srow = tid >> 5;                 // 0..15
  const int skol = (tid & 31) << 2;          // 0,4,...,124

  float* h0base = ws;
  float* h1base = ws + (size_t)P * NB;
  float* igbase = ws + (size_t)2 * P * NB;
  unsigned* bar = (unsigned*)(ws + (size_t)3 * P * NB);

  const float* W = (role == 3) ? Wx
                 : (role == 0) ? Wh
                 : (role == 1) ? (Wx + (size_t)HID * HID)
                 :               (Wh + (size_t)HID * HID);
  // Wave q's k-elements within chunk cc: k = cc*128 + q*16 + j, j=0..15.
  const float* Wb = W + (size_t)c0 * HID + kq * 16;

  // This thread's LDS read row (conflict-free with HSTRIDE=132).
  const float* hr = &hbuf[b * HSTRIDE + kq * 16];

  // Epilogue output assignment: 2 outputs per thread, o = 2*tid, 2*tid+1.
  const int o0 = tid * 2;
  const int b1 = o0 >> 4;                    // batch row of outputs
  const int c1 = o0 & 15;                    // local col (even)
  const size_t rb = (size_t)b1 * HID + c0 + c1;

  float bsum0 = 0.f, bsum1 = 0.f;
  if (role == 1) {
    bsum0 = bx[HID + c0 + c1]     + bh[HID + c0 + c1];
    bsum1 = bx[HID + c0 + c1 + 1] + bh[HID + c0 + c1 + 1];
  } else if (role == 3) {
    bsum0 = bx[c0 + c1]     + bh[c0 + c1];
    bsum1 = bx[c0 + c1 + 1] + bh[c0 + c1 + 1];
  }

  for (int i = 0; i < NITER; ++i) {
    // Periodic coherence fence (grid-uniform): see model above.
    if ((i & (int)mask) == 0 && i) {
      __builtin_amdgcn_fence(__ATOMIC_ACQUIRE, "agent");
    }

    bool active;
    int t;
    const float* src;
    if (role == 3)      { t = i;     active = (i <= 511);           src = x + (size_t)t * NB; }
    else if (role == 0) { t = i - 1; active = (i >= 1 && i <= 512);
                          src = (t == 0) ? h0_init : h0base + (size_t)((t - 1) & mask) * NB; }
    else if (role == 1) { t = i - 2; active = (i >= 2 && i <= 513);
                          src = h0base + (size_t)(t & mask) * NB; }
    else                { t = i - 3; active = (i >= 3 && i <= 514);
                          src = (t == 0) ? (h0_init + NB) : h1base + (size_t)((t - 1) & mask) * NB; }

    if (active) {
      // Epilogue operands (produced >=1 iteration ago; plain cached loads).
      float e0 = 0.f, e1 = 0.f;
      if (role == 0)      { e0 = io[(size_t)t * NB + rb];
                            e1 = io[(size_t)t * NB + rb + 1]; }
      else if (role == 2) { const float* ig = igbase + (size_t)(t & mask) * NB;
                            e0 = ig[rb]; e1 = ig[rb + 1]; }

      f32x2 acc[16];
#pragma unroll
      for (int c = 0; c < 16; ++c) acc[c] = f32x2{0.f, 0.f};

      // Two-phase double-buffered chunk pipeline. stA/stB are only ever
      // referenced by NAME with static indices -> register-resident
      // (R5's runtime pointer-select sent them to scratch: rule #20).
      float4 stA[4], stB[4];
      load_chunk(stA, src, srow, skol, 0);
#pragma unroll 1
      for (int dc = 0; dc < 4; ++dc) {
        const int ccA = dc * 2;
        __syncthreads();                       // prior chunk's LDS reads done
        write_chunk(hbuf, stA, srow, skol);
        load_chunk(stB, src, srow, skol, ccA + 1);   // prefetch odd chunk
        __syncthreads();                       // hbuf(even) visible
        compute_chunk(acc, hr, Wb + (size_t)ccA * 128);
        __syncthreads();                       // even-chunk reads done
        write_chunk(hbuf, stB, srow, skol);
        if (dc < 3)
          load_chunk(stA, src, srow, skol, ccA + 2); // prefetch next even
        __syncthreads();                       // hbuf(odd) visible
        compute_chunk(acc, hr, Wb + (size_t)(ccA + 1) * 128);
      }

      // Collapse even/odd-k partials, then kq-reduction through LDS.
      float accs[16];
#pragma unroll
      for (int c = 0; c < 16; ++c) accs[c] = acc[c].x + acc[c].y;

      float* rrow = &red[(kq * 64 + b) * RSTRIDE];
      *(float4*)(rrow + 0)  = make_float4(accs[0],  accs[1],  accs[2],  accs[3]);
      *(float4*)(rrow + 4)  = make_float4(accs[4],  accs[5],  accs[6],  accs[7]);
      *(float4*)(rrow + 8)  = make_float4(accs[8],  accs[9],  accs[10], accs[11]);
      *(float4*)(rrow + 12) = make_float4(accs[12], accs[13], accs[14], accs[15]);
      __syncthreads();

      float s0 = 0.f, s1 = 0.f;
#pragma unroll
      for (int q = 0; q < 8; ++q) {
        s0 += red[(q * 64 + b1) * RSTRIDE + c1];
        s1 += red[(q * 64 + b1) * RSTRIDE + c1 + 1];
      }

      if (role == 3) {
        f32x2 o = { s0 + bsum0, s1 + bsum1 };
        gstore2_coh(io + (size_t)t * NB + rb, o);
      } else if (role == 0) {
        f32x2 o = { tanhf(s0 + e0), tanhf(s1 + e1) };
        gstore2_coh(h0base + (size_t)(t & mask) * NB + rb, o);
      } else if (role == 1) {
        f32x2 o = { s0 + bsum0, s1 + bsum1 };
        gstore2_coh(igbase + (size_t)(t & mask) * NB + rb, o);
      } else {
        float t0 = tanhf(s0 + e0);
        float t1 = tanhf(s1 + e1);
        f32x2 o = { t0, t1 };
        gstore2_coh(h1base + (size_t)(t & mask) * NB + rb, o);
        // Final output: plain store; kernel-end release flushes dirty L2.
        *(float2*)&io[(size_t)t * NB + rb] = make_float2(10.f * t0, 10.f * t1);
      }
      // red/hbuf reuse next iter is fenced by gbar's __syncthreads.
    }
    gbar(bar, (unsigned)(NBLK * (i + 1)));
  }
}

// ---------------------------------------------------------------------------
// Finalize: h_n = [h0[511], h1[511]] (slot 511&mask; written by sc1
// write-through stores -> fresh at the MALL; this dispatch's acquire
// invalidates caches so plain loads see it).
// ---------------------------------------------------------------------------
__global__ __launch_bounds__(256) void finalize_hn(
    const float* __restrict__ ws, float* __restrict__ out, unsigned P, unsigned mask)
{
  const int g = blockIdx.x * 256 + threadIdx.x;     // 0..131071
  const float* h0f = ws + (size_t)(511u & mask) * NB;
  const float* h1f = ws + (size_t)(P + (511u & mask)) * NB;
  const float v = (g < NB) ? h0f[g] : h1f[g - NB];
  out[(size_t)TSEQ * NB + g] = v;
}

// ---------------------------------------------------------------------------
extern "C" void kernel_launch(void* const* d_in, const int* in_sizes, int n_in,
                              void* d_out, int out_size, void* d_ws, size_t ws_size,
                              hipStream_t stream) {
  const float* x  = (const float*)d_in[0];
  const float* h0 = (const float*)d_in[1];
  const float* Wx = (const float*)d_in[2];
  const float* bx = (const float*)d_in[3];
  const float* Wh = (const float*)d_in[4];
  const float* bh = (const float*)d_in[5];
  float* out = (float*)d_out;
  float* ws  = (float*)d_ws;

  // Pick the deepest slot rotation that fits the workspace (16 -> 12.6 MB).
  // P=2 floor has byte-identical footprint to the previously-verified layout.
  unsigned P = 16;
  while (P > 2 && ((size_t)3 * P * NB + 16) * sizeof(float) > ws_size) P >>= 1;
  unsigned mask = P - 1;

  // Zero the barrier counter (stream-ordered, graph-capture safe).
  hipMemsetAsync(ws + (size_t)3 * P * NB, 0, sizeof(unsigned), stream);

  float* io = out;
  void* args[] = { &x, &io, &h0, &Wx, &Wh, &bx, &bh, &ws, &P, &mask };
  hipLaunchCooperativeKernel((const void*)rnn_step, dim3(NBLK), dim3(512),
                             args, 0, stream);

  finalize_hn<<<dim3(512), dim3(256), 0, stream>>>(ws, out, P, mask);
}

// Round 7
// 17845.541 us; speedup vs baseline: 2.1006x; 1.8775x over previous
//
#include <hip/hip_runtime.h>
#include <cstddef>
#include <cstdint>

#define HID     1024
#define BATCH   64
#define TSEQ    512
#define NB      (BATCH*HID)     // 65536 floats per slab
#define NBLK    256
#define NITER   515
#define RSTRIDE 20              // LDS reduction row stride (16 + pad 4)

// ---------------------------------------------------------------------------
// R7: revert to the R4 structure (18.9 ms, best verified) + TRANSPOSED slabs.
//
// ws layout (floats), P = slot rotation depth (16/8/4/2 chosen from ws_size):
//  [0,        P*NB)   h0T slots  (slot t&(P-1) holds h0[t], layout [H][B])
//  [P*NB,   2*P*NB)   h1T slots  (layout [H][B])
//  [2*P*NB, 3*P*NB)   ig1T slots (layout [H][B])
//  [3*P*NB]           barrier counter
//  io[t]: holds ig0T[t] ([H][B]) until role 2 overwrites it with the final
//         output ([B][H]) at i=t+3. Full-slab overwrite; byte-masked L2
//         writebacks make cross-XCD partial-line writes safe (standard HIP).
//
// Why transpose: R4's slab reads were lane<->batch (4KB lane stride): every
// dwordx4 touched 64 distinct 128B lines, and R4's duration matched its
// 585 GB/s effective fetch rate -> line-fetch-rate limited. Transposed,
// thread (b,kq) reads hT[k*64+b]: 64 lanes x 4B = one 256B segment
// (2 lines/inst, 32x fewer line touches, full line utilization), no LDS
// staging needed (R5/R6's staging structure measured 33-37ms; dead end).
//
// Coherence (R4-verified): sc1 write-through stores for cross-block slabs;
// plain cached loads; agent-acquire fence every P iters kills any cached
// slab line before its slot is re-read. h0_init is pre-transposed into
// slot `mask` by init_hT (separate dispatch -> visible), removing the
// t==0 special case.
// ---------------------------------------------------------------------------

typedef __attribute__((ext_vector_type(4))) float f32x4;
typedef __attribute__((ext_vector_type(2))) float f32x2;

#define WAITV(N) do { asm volatile("s_waitcnt vmcnt(" #N ")" ::: "memory"); \
                      __builtin_amdgcn_sched_barrier(0); } while (0)

__device__ __forceinline__ f32x4 gload4(const float* p) {
  f32x4 v;
  asm volatile("global_load_dwordx4 %0, %1, off" : "=v"(v) : "v"(p) : "memory");
  return v;
}

__device__ __forceinline__ float gload1(const float* p) {
  float v;
  asm volatile("global_load_dword %0, %1, off" : "=v"(v) : "v"(p) : "memory");
  return v;
}

__device__ __forceinline__ void gstore2_coh(float* p, f32x2 v) {
  asm volatile("global_store_dwordx2 %0, %1, off sc1" :: "v"(p), "v"(v) : "memory");
}

__device__ __forceinline__ void gbar(unsigned* bar, unsigned target) {
  asm volatile("s_waitcnt vmcnt(0)" ::: "memory");
  __syncthreads();
  if (threadIdx.x == 0) {
    __hip_atomic_fetch_add(bar, 1u, __ATOMIC_RELAXED, __HIP_MEMORY_SCOPE_AGENT);
    while (__hip_atomic_load(bar, __ATOMIC_RELAXED, __HIP_MEMORY_SCOPE_AGENT) < target) {
      __builtin_amdgcn_s_sleep(1);
    }
  }
  __syncthreads();
}

// --- engine A: transposed-slab reads (roles 0,1,2) --------------------------
// 16 coalesced dword loads per 16-k sub-chunk, A/B double-buffered with
// counted vmcnt. hTb = slabT + b (lane-varying), k indexed as (k0+j)*64.
__device__ __forceinline__ void load16(float (&A)[16], const float* hTb, int k0) {
#pragma unroll
  for (int j = 0; j < 16; ++j) A[j] = gload1(hTb + (size_t)(k0 + j) * 64);
}

__device__ __forceinline__ void fma16t(f32x2 (&acc)[16], const float (&h)[16], const float* Wc) {
#pragma unroll 4
  for (int c = 0; c < 16; ++c) {
    const float* w = Wc + (size_t)c * HID;   // wave-uniform -> s_load
    float4 w0 = *(const float4*)(w + 0);
    float4 w1 = *(const float4*)(w + 4);
    float4 w2 = *(const float4*)(w + 8);
    float4 w3 = *(const float4*)(w + 12);
    f32x2 s = acc[c];
    s += f32x2{h[0],  h[1]}  * f32x2{w0.x, w0.y};
    s += f32x2{h[2],  h[3]}  * f32x2{w0.z, w0.w};
    s += f32x2{h[4],  h[5]}  * f32x2{w1.x, w1.y};
    s += f32x2{h[6],  h[7]}  * f32x2{w1.z, w1.w};
    s += f32x2{h[8],  h[9]}  * f32x2{w2.x, w2.y};
    s += f32x2{h[10], h[11]} * f32x2{w2.z, w2.w};
    s += f32x2{h[12], h[13]} * f32x2{w3.x, w3.y};
    s += f32x2{h[14], h[15]} * f32x2{w3.z, w3.w};
    acc[c] = s;
  }
}

__device__ __forceinline__ void dot_engine_T(const float* hTb, const float* Wb,
                                             int k0, f32x2 (&acc)[16]) {
  float A[16], B[16];
  load16(A, hTb, k0);
  load16(B, hTb, k0 + 16);
  WAITV(16); fma16t(acc, A, Wb);
  load16(A, hTb, k0 + 32);
  WAITV(16); fma16t(acc, B, Wb + 16);
  load16(B, hTb, k0 + 48);
  WAITV(16); fma16t(acc, A, Wb + 32);
  load16(A, hTb, k0 + 64);
  WAITV(16); fma16t(acc, B, Wb + 48);
  load16(B, hTb, k0 + 80);
  WAITV(16); fma16t(acc, A, Wb + 64);
  load16(A, hTb, k0 + 96);
  WAITV(16); fma16t(acc, B, Wb + 80);
  load16(B, hTb, k0 + 112);
  WAITV(16); fma16t(acc, A, Wb + 96);
  WAITV(0);  fma16t(acc, B, Wb + 112);
}

// --- engine B: [B][H] reads for x (role 3) — R4's verified engine -----------
__device__ __forceinline__ void fma16x4(f32x2 (&acc)[16], const f32x4 (&h)[8], const float* Wc) {
#pragma unroll 4
  for (int c = 0; c < 16; ++c) {
    const float* w = Wc + (size_t)c * HID;
    f32x2 s = acc[c];
#pragma unroll
    for (int r = 0; r < 8; ++r) {
      float4 wv = *(const float4*)(w + r * 4);
      s += f32x2{h[r].x, h[r].y} * f32x2{wv.x, wv.y};
      s += f32x2{h[r].z, h[r].w} * f32x2{wv.z, wv.w};
    }
    acc[c] = s;
  }
}

__device__ __forceinline__ void dot_engine_x(const float* hb, const float* Wb, f32x2 (&acc)[16]) {
  f32x4 A[8], B[8];
#pragma unroll
  for (int r = 0; r < 8; ++r) A[r] = gload4(hb + r * 4);
#pragma unroll
  for (int r = 0; r < 8; ++r) B[r] = gload4(hb + 32 + r * 4);
  WAITV(8); fma16x4(acc, A, Wb);
#pragma unroll
  for (int r = 0; r < 8; ++r) A[r] = gload4(hb + 64 + r * 4);
  WAITV(8); fma16x4(acc, B, Wb + 32);
#pragma unroll
  for (int r = 0; r < 8; ++r) B[r] = gload4(hb + 96 + r * 4);
  WAITV(8); fma16x4(acc, A, Wb + 64);
  WAITV(0); fma16x4(acc, B, Wb + 96);
}

// ---------------------------------------------------------------------------
// init_hT: pre-transpose h0_init ([2][B][H]) into slot `mask` of h0T/h1T.
// ---------------------------------------------------------------------------
__global__ __launch_bounds__(256) void init_hT(
    const float* __restrict__ h0_init, float* __restrict__ ws,
    unsigned P, unsigned mask)
{
  const int g = blockIdx.x * 256 + threadIdx.x;   // 0..131071 (grid 512)
  const int l = g >> 16;
  const int r = g & 65535;                        // r = k*64 + b
  const int k = r >> 6;
  const int b = r & 63;
  float* base = ws + (size_t)l * P * NB + (size_t)mask * NB;
  base[r] = h0_init[(size_t)l * NB + (size_t)b * HID + k];  // coalesced write
}

// ---------------------------------------------------------------------------
// Persistent cooperative pipelined recurrence, 256 blocks x 512 threads.
// Roles (blk>>6), iteration i:
//   3: ig0T[t=i]   = (x[t] @ Wx0^T + b)^T          -> io[t]     (sc1)
//   0: h0T[t=i-1]  = tanh(ig0T[t] + (h0[t-1]@Wh0^T)^T) -> slot  (sc1)
//   1: ig1T[t=i-2] = (h0[t] @ Wx1^T + b)^T         -> slot      (sc1)
//   2: h1T[t=i-3]  = tanh(ig1T[t] + ...) -> slot (sc1); io[t] = 10*h1 [B][H]
// ---------------------------------------------------------------------------
__global__ __launch_bounds__(512, 2) void rnn_step(
    const float* __restrict__ x,
    float* io,
    const float* __restrict__ Wx,       // [2][H][H]
    const float* __restrict__ Wh,       // [2][H][H]
    const float* __restrict__ bx,       // [2][H]
    const float* __restrict__ bh,       // [2][H]
    float* __restrict__ ws,
    unsigned P, unsigned mask)
{
  __shared__ __align__(16) float red[8 * 64 * RSTRIDE];   // 40 KB
  const int tid  = threadIdx.x;
  const int blk  = blockIdx.x;
  const int role = blk >> 6;                 // 0..3
  const int c0   = (blk & 63) << 4;          // 16 cols per block
  const int b    = tid & 63;                 // compute lane = batch row
  const int kq   = __builtin_amdgcn_readfirstlane(tid >> 6); // wave 0..7
  const int k0   = kq * 128;                 // this wave's K-slice

  float* h0base = ws;
  float* h1base = ws + (size_t)P * NB;
  float* igbase = ws + (size_t)2 * P * NB;
  unsigned* bar = (unsigned*)(ws + (size_t)3 * P * NB);

  const float* W = (role == 3) ? Wx
                 : (role == 0) ? Wh
                 : (role == 1) ? (Wx + (size_t)HID * HID)
                 :               (Wh + (size_t)HID * HID);
  const float* Wb = W + (size_t)c0 * HID + k0;

  // Epilogue mapping: thread -> (col cE, batches bE,bE+1); transposed slab
  // offset rbT -> coalesced dwordx2 (2 contiguous 256B runs per wave).
  const int cE = tid >> 5;                   // 0..15
  const int bE = (tid & 31) << 1;            // 0..62 even
  const size_t rbT = (size_t)(c0 + cE) * 64 + bE;

  float bsum = 0.f;
  if (role == 1)      bsum = bx[HID + c0 + cE] + bh[HID + c0 + cE];
  else if (role == 3) bsum = bx[c0 + cE]       + bh[c0 + cE];

  for (int i = 0; i < NITER; ++i) {
    if ((i & (int)mask) == 0 && i) {
      __builtin_amdgcn_fence(__ATOMIC_ACQUIRE, "agent");   // every P iters
    }

    bool active;
    int t;
    const float* src;
    if (role == 3)      { t = i;     active = (i <= 511);           src = x + (size_t)t * NB; }
    else if (role == 0) { t = i - 1; active = (i >= 1 && i <= 512);
                          src = h0base + (size_t)((t - 1) & (int)mask) * NB; }  // t=0 -> slot mask (init)
    else if (role == 1) { t = i - 2; active = (i >= 2 && i <= 513);
                          src = h0base + (size_t)(t & (int)mask) * NB; }
    else                { t = i - 3; active = (i >= 3 && i <= 514);
                          src = h1base + (size_t)((t - 1) & (int)mask) * NB; }  // t=0 -> slot mask (init)

    if (active) {
      f32x2 acc[16];
#pragma unroll
      for (int c = 0; c < 16; ++c) acc[c] = f32x2{0.f, 0.f};

      if (role == 3) dot_engine_x(src + (size_t)b * HID + k0, Wb, acc);
      else           dot_engine_T(src + b, Wb, k0, acc);

      // Epilogue operands (all asm loads drained by engine's WAITV(0) ->
      // these plain loads get clean compiler-managed waits).
      f32x2 e = { 0.f, 0.f };
      if (role == 0)      e = *(const f32x2*)(io + (size_t)t * NB + rbT);
      else if (role == 2) e = *(const f32x2*)(igbase + (size_t)(t & (int)mask) * NB + rbT);

      // Collapse even/odd-k partials, kq-reduction through LDS.
      float accs[16];
#pragma unroll
      for (int c = 0; c < 16; ++c) accs[c] = acc[c].x + acc[c].y;

      float* rrow = &red[(kq * 64 + b) * RSTRIDE];
      *(float4*)(rrow + 0)  = make_float4(accs[0],  accs[1],  accs[2],  accs[3]);
      *(float4*)(rrow + 4)  = make_float4(accs[4],  accs[5],  accs[6],  accs[7]);
      *(float4*)(rrow + 8)  = make_float4(accs[8],  accs[9],  accs[10], accs[11]);
      *(float4*)(rrow + 12) = make_float4(accs[12], accs[13], accs[14], accs[15]);
      __syncthreads();

      float s0 = 0.f, s1 = 0.f;
#pragma unroll
      for (int q = 0; q < 8; ++q) {
        s0 += red[(q * 64 + bE)     * RSTRIDE + cE];
        s1 += red[(q * 64 + bE + 1) * RSTRIDE + cE];
      }

      if (role == 3) {
        gstore2_coh(io + (size_t)t * NB + rbT, f32x2{ s0 + bsum, s1 + bsum });
      } else if (role == 0) {
        gstore2_coh(h0base + (size_t)(t & (int)mask) * NB + rbT,
                    f32x2{ tanhf(s0 + e.x), tanhf(s1 + e.y) });
      } else if (role == 1) {
        gstore2_coh(igbase + (size_t)(t & (int)mask) * NB + rbT,
                    f32x2{ s0 + bsum, s1 + bsum });
      } else {
        float t0 = tanhf(s0 + e.x);
        float t1 = tanhf(s1 + e.y);
        gstore2_coh(h1base + (size_t)(t & (int)mask) * NB + rbT, f32x2{ t0, t1 });
        // Final output in [B][H] (required layout): plain divergent stores,
        // fire-and-forget; flushed at kernel-end release.
        io[(size_t)t * NB + (size_t)bE       * HID + c0 + cE] = 10.f * t0;
        io[(size_t)t * NB + (size_t)(bE + 1) * HID + c0 + cE] = 10.f * t1;
      }
    }
    gbar(bar, (unsigned)(NBLK * (i + 1)));
  }
}

// ---------------------------------------------------------------------------
// Finalize: h_n[l][b][k] = hT_l[slot 511&mask][k*64+b].
// ---------------------------------------------------------------------------
__global__ __launch_bounds__(256) void finalize_hn(
    const float* __restrict__ ws, float* __restrict__ out, unsigned P, unsigned mask)
{
  const int g = blockIdx.x * 256 + threadIdx.x;     // 0..131071
  const int l = g >> 16;
  const int rem = g & 65535;                        // b*1024 + k
  const int bb = rem >> 10;
  const int kk = rem & 1023;
  const float* hf = ws + ((size_t)l * P + (511u & mask)) * NB;
  out[(size_t)TSEQ * NB + g] = hf[(size_t)kk * 64 + bb];
}

// ---------------------------------------------------------------------------
extern "C" void kernel_launch(void* const* d_in, const int* in_sizes, int n_in,
                              void* d_out, int out_size, void* d_ws, size_t ws_size,
                              hipStream_t stream) {
  const float* x  = (const float*)d_in[0];
  const float* h0 = (const float*)d_in[1];
  const float* Wx = (const float*)d_in[2];
  const float* bx = (const float*)d_in[3];
  const float* Wh = (const float*)d_in[4];
  const float* bh = (const float*)d_in[5];
  float* out = (float*)d_out;
  float* ws  = (float*)d_ws;

  unsigned P = 16;
  while (P > 2 && ((size_t)3 * P * NB + 16) * sizeof(float) > ws_size) P >>= 1;
  unsigned mask = P - 1;

  hipMemsetAsync(ws + (size_t)3 * P * NB, 0, sizeof(unsigned), stream);
  init_hT<<<dim3(512), dim3(256), 0, stream>>>(h0, ws, P, mask);

  float* io = out;
  void* args[] = { &x, &io, &Wx, &Wh, &bx, &bh, &ws, &P, &mask };
  hipLaunchCooperativeKernel((const void*)rnn_step, dim3(NBLK), dim3(512),
                             args, 0, stream);

  finalize_hn<<<dim3(512), dim3(256), 0, stream>>>(ws, out, P, mask);
}